// Round 1
// 129.440 us; speedup vs baseline: 1.0406x; 1.0406x over previous
//
#include <hip/hip_runtime.h>
#include <math.h>

// RandomLowRes2D: per-image Gaussian blur (R=15, symmetric pad) + linear
// down/up resample along a per-image runtime axis.
//
// Fusion: low[j] = (1-fr)*s[la] + fr*s[la+1] collapses blur+downsample into a
// single fused filter on img: cw[k] = fmaf(fr, dwe[k], we[k+1]),
// with dwe[k] = we[k] - we[k+1] precomputed.
//
// Round 5 (instruction-count reduction in the blur tap loops):
//  - weight tables fused into one float2 wd[k] = {we[k+1], dwe[k]}:
//    per tap 2x ds_read_b32 -> 1x ds_read_b64 (both paths).
//  - ax0 path float2 -> float4 per lane (16 B/lane loads), block split into
//    2 groups of 128 lanes x 4 rows each: VMEM instructions and per-byte
//    VALU address math halved; 4 independent FMA chains per tap (ILP).
//  - ax0 chain scalarized: readfirstlane on group id and `la` puts the
//    per-tap address arithmetic on the SALU (s_add parallel to VALU).
//  - numerics identical to round 4 (same FMA order, exact IEEE divides).

#define RR 15
#define TAPS 31
#define SEG0 8                   // ax0: output rows per block (64 blocks/img)
#define SIG_PER_FWHM 0.42466090014400953f  // 1/sqrt(8 ln 2)

__global__ __launch_bounds__(256) void lowres2d_kernel(
    const float* __restrict__ x,
    const float* __restrict__ resolution,
    const int*   __restrict__ axis,
    const float* __restrict__ gap,
    float* __restrict__ out)
{
    const int tid = threadIdx.x;
    const int n   = blockIdx.y;          // image index
    const int bx  = blockIdx.x;          // 0..127

    const float res = resolution[n];
    const int   ax  = axis[n];
    const float gp  = gap[n];

    // ax0 images use 64 blocks (2 groups x 4 rows); rest exit (block-uniform)
    if (ax == 0 && bx >= 64) return;

    const float sig = fmaxf(res * gp * SIG_PER_FWHM, 1e-6f);
    int n_low = (int)floorf(512.0f / res);
    if (n_low < 1) n_low = 1;
    if (n_low > 512) n_low = 512;
    const float nlm1f = (float)(n_low - 1);

    // adaptive radius: normalized weights < 1e-6 outside +-kr (sum >= 1)
    int kr = (int)(sig * 5.2565f) + 1;
    if (kr > RR) kr = RR;
    const int k0 = RR - kr, k1 = RR + 1 + kr;   // fused window k in [k0, k1]
    const int la_lo = kr, la_hi = 510 - kr;     // interior: no reflect needed

    // wd[k] = { we[k+1], dwe[k] }, k = 0..31; we[0]=we[32]=0 implicit
    __shared__ float2 wd[32];
    __shared__ float s_img[4][520];      // ax1: input tile
    __shared__ float s_low[4][516];      // ax1: low-res intermediate

    if (tid < 32) {
        const int k = tid;
        float r = 0.0f;
        if (k < TAPS) {
            float d = (float)(k - RR) / sig;
            r = expf(-0.5f * d * d);
        }
        float tot = r;
        tot += __shfl_xor(tot, 1, 32);
        tot += __shfl_xor(tot, 2, 32);
        tot += __shfl_xor(tot, 4, 32);
        tot += __shfl_xor(tot, 8, 32);
        tot += __shfl_xor(tot, 16, 32);
        float rm1 = __shfl_up(r, 1, 32);
        if (k == 0) rm1 = 0.0f;
        const float inv = 1.0f / tot;            // tot >= 1 (center tap)
        wd[k] = make_float2(r * inv, (rm1 - r) * inv);
    }
    __syncthreads();

    const size_t base = (size_t)n * (512 * 512);
    const float* img = x + base;
    float* o = out + base;

    if (ax == 0) {
        // ---- ax0: streaming, coalesced, float4/lane, 2 groups x 4 rows ----
        const int lt = tid & 127;                      // col4: cols 4*lt..4*lt+3
        const int g  = __builtin_amdgcn_readfirstlane(tid >> 7); // group 0/1
        const int i0 = bx * SEG0 + g * 4;
        const float4* img4 = (const float4*)img;
        float4* out4 = (float4*)o;

        auto compute_low = [&](int j) -> float4 {
            float pos = fminf((float)j * res, 511.0f);
            float lof = floorf(pos);
            float fr  = pos - lof;
            int   la  = __builtin_amdgcn_readfirstlane((int)lof);
            float4 acc = make_float4(0.0f, 0.0f, 0.0f, 0.0f);
            if (la >= la_lo && la <= la_hi) {        // group-uniform branch
                #pragma unroll 4
                for (int k = k0; k <= k1; ++k) {
                    int t = la - RR + k;             // scalar
                    float2 w = wd[k];
                    float cw = fmaf(fr, w.y, w.x);
                    float4 v = img4[(size_t)(t * 128 + lt)];
                    acc.x = fmaf(cw, v.x, acc.x);
                    acc.y = fmaf(cw, v.y, acc.y);
                    acc.z = fmaf(cw, v.z, acc.z);
                    acc.w = fmaf(cw, v.w, acc.w);
                }
            } else {
                for (int k = k0; k <= k1; ++k) {
                    int t = la - RR + k;
                    t = (t < 0)   ? (-1 - t)   : t;  // symmetric reflect
                    t = (t > 511) ? (1023 - t) : t;
                    float2 w = wd[k];
                    float cw = fmaf(fr, w.y, w.x);
                    float4 v = img4[(size_t)(t * 128 + lt)];
                    acc.x = fmaf(cw, v.x, acc.x);
                    acc.y = fmaf(cw, v.y, acc.y);
                    acc.z = fmaf(cw, v.z, acc.z);
                    acc.w = fmaf(cw, v.w, acc.w);
                }
            }
            return acc;
        };

        float p0 = fminf((float)i0 / res, nlm1f);
        int j = (int)floorf(p0);
        if (j > n_low - 1) j = n_low - 1;
        j = __builtin_amdgcn_readfirstlane(j);
        float4 lowA = compute_low(j);
        int jB = (j + 1 < n_low) ? (j + 1) : (n_low - 1);
        float4 lowB = (jB == j) ? lowA : compute_low(jB);

        for (int i = i0; i < i0 + 4; ++i) {
            float pos2 = fminf((float)i / res, nlm1f);  // exact IEEE div
            float l2f  = floorf(pos2);
            float fr2  = pos2 - l2f;
            int lo2 = (int)l2f;
            if (lo2 > n_low - 1) lo2 = n_low - 1;

            if (lo2 == j + 1) {
                j = lo2;
                lowA = lowB;
                jB = (j + 1 < n_low) ? (j + 1) : (n_low - 1);
                lowB = (jB == j) ? lowA : compute_low(jB);
            } else if (lo2 > j + 1) {
                j = lo2;
                lowA = compute_low(j);
                jB = (j + 1 < n_low) ? (j + 1) : (n_low - 1);
                lowB = (jB == j) ? lowA : compute_low(jB);
            }
            float omf2 = 1.0f - fr2;
            float4 ov;
            ov.x = lowA.x * omf2 + lowB.x * fr2;
            ov.y = lowA.y * omf2 + lowB.y * fr2;
            ov.z = lowA.z * omf2 + lowB.z * fr2;
            ov.w = lowA.w * omf2 + lowB.w * fr2;
            out4[(size_t)(i * 128 + lt)] = ov;
        }
    } else {
        // ---------------- ax1: LDS-tiled 4 rows, coalesced ----------------
        const int h0 = bx * 4;

        // load 4x512 tile, float4 coalesced (512 float4 over 256 threads)
        const float4* img4 = (const float4*)(img + (size_t)h0 * 512);
        #pragma unroll
        for (int p = 0; p < 2; ++p) {
            int m = p * 256 + tid;
            int r = m >> 7, c4 = m & 127;
            ((float4*)&s_img[r][0])[c4] = img4[r * 128 + c4];
        }
        __syncthreads();

        // compute lows: one wave per row (r uniform per wave), j strided 64
        {
            const int r = __builtin_amdgcn_readfirstlane(tid >> 6);
            for (int j = (tid & 63); j < n_low; j += 64) {
                float pos = fminf((float)j * res, 511.0f);
                float lof = floorf(pos);
                float fr  = pos - lof;
                int   la  = (int)lof;
                float acc = 0.0f;
                if (la >= la_lo && la <= la_hi) {
                    #pragma unroll 4
                    for (int k = k0; k <= k1; ++k) {
                        int t = la - RR + k;
                        float2 w = wd[k];
                        float cw = fmaf(fr, w.y, w.x);
                        acc = fmaf(cw, s_img[r][t], acc);
                    }
                } else {
                    for (int k = k0; k <= k1; ++k) {
                        int t = la - RR + k;
                        t = (t < 0)   ? (-1 - t)   : t;
                        t = (t > 511) ? (1023 - t) : t;
                        float2 w = wd[k];
                        float cw = fmaf(fr, w.y, w.x);
                        acc = fmaf(cw, s_img[r][t], acc);
                    }
                }
                s_low[r][j] = acc;
            }
        }
        __syncthreads();

        // upsample + coalesced float4 stores
        float4* out4 = (float4*)(o + (size_t)h0 * 512);
        #pragma unroll
        for (int p = 0; p < 2; ++p) {
            int m = p * 256 + tid;
            int r = m >> 7, c4 = m & 127;
            float vals[4];
            #pragma unroll
            for (int q = 0; q < 4; ++q) {
                int i = c4 * 4 + q;
                float pos2 = fminf((float)i / res, nlm1f);
                float l2f  = floorf(pos2);
                float fr2  = pos2 - l2f;
                int lo2 = (int)l2f;
                if (lo2 > n_low - 1) lo2 = n_low - 1;
                int hi2 = (lo2 + 1 < n_low) ? (lo2 + 1) : (n_low - 1);
                vals[q] = s_low[r][lo2] * (1.0f - fr2) + s_low[r][hi2] * fr2;
            }
            float4 ov;
            ov.x = vals[0]; ov.y = vals[1]; ov.z = vals[2]; ov.w = vals[3];
            out4[r * 128 + c4] = ov;
        }
    }
}

extern "C" void kernel_launch(void* const* d_in, const int* in_sizes, int n_in,
                              void* d_out, int out_size, void* d_ws, size_t ws_size,
                              hipStream_t stream) {
    const float* x          = (const float*)d_in[0];
    const float* resolution = (const float*)d_in[1];
    const int*   axis       = (const int*)d_in[2];
    const float* gap        = (const float*)d_in[3];
    float* out = (float*)d_out;

    const int n_img = in_sizes[1];   // B*C = 64

    dim3 grid(128, n_img);
    lowres2d_kernel<<<grid, 256, 0, stream>>>(x, resolution, axis, gap, out);
}